// Round 2
// baseline (384.282 us; speedup 1.0000x reference)
//
#include <hip/hip_runtime.h>
#include <math.h>

#define NB 32
#define NV 2048
#define NC 64
#define NT 64
#define VC 32           // v-values per block in kernel 1

// ---------------------------------------------------------------------------
// Kernel 1: one pass over x (1 GiB). Each block handles (b, chunk of VC v's).
// Produces (via global atomicAdd):
//   tmp1[b,c,t] = sum_v x[b,v,c,t] * U1[v]
//   M[b,c,u]    = sum_v U2[c,v] * rhs[b,v,u],  rhs[b,v,u] = sum_c x[b,v,c,u]*U3[c]
// Thread mapping: t4 = tid&15 (float4 column group), cg = tid>>4, c = cg*4..cg*4+3.
// tmp1 and M fragments live in registers across the v-loop (16 floats each).
// ---------------------------------------------------------------------------
__global__ __launch_bounds__(256) void k1_pass_x(
    const float* __restrict__ x,
    const float* __restrict__ U1,
    const float* __restrict__ U2,   // (C, V)
    const float* __restrict__ U3,   // (C)
    float* __restrict__ tmp1g,      // (B, C, T), pre-zeroed
    float* __restrict__ Mg)         // (B, C, T), pre-zeroed
{
    const int tid = threadIdx.x;
    const int blk = blockIdx.x;
    const int b      = blk / (NV / VC);
    const int vchunk = blk % (NV / VC);
    const int v0     = vchunk * VC;

    const int t4 = tid & 15;   // float4 group along t (t = t4*4 .. t4*4+3)
    const int cg = tid >> 4;   // 0..15
    const int c0 = cg * 4;

    __shared__ float rp[16][NT];     // [cg][t] partial rhs
    __shared__ float rhs_s[NT];      // reduced rhs for current v
    __shared__ float U2s[NC][VC];    // staged U2 chunk

    // stage U2[c][v0..v0+VC) into LDS
    for (int i = tid; i < NC * VC; i += 256) {
        int c = i / VC, vi = i % VC;
        U2s[c][vi] = U2[c * NV + v0 + vi];
    }

    float u3r[4];
#pragma unroll
    for (int k = 0; k < 4; ++k) u3r[k] = U3[c0 + k];

    float4 t1r[4], mr[4];
#pragma unroll
    for (int k = 0; k < 4; ++k) {
        t1r[k] = make_float4(0.f, 0.f, 0.f, 0.f);
        mr[k]  = make_float4(0.f, 0.f, 0.f, 0.f);
    }

    __syncthreads();

    const float* xbase = x + (size_t)(b * NV + v0) * NC * NT;

    for (int vi = 0; vi < VC; ++vi) {
        const float u1v = U1[v0 + vi];
        const float* xv = xbase + (size_t)vi * NC * NT;

        float4 xa[4];
#pragma unroll
        for (int k = 0; k < 4; ++k)
            xa[k] = *reinterpret_cast<const float4*>(xv + (c0 + k) * NT + t4 * 4);

        float4 rh = make_float4(0.f, 0.f, 0.f, 0.f);
#pragma unroll
        for (int k = 0; k < 4; ++k) {
            t1r[k].x = fmaf(u1v, xa[k].x, t1r[k].x);
            t1r[k].y = fmaf(u1v, xa[k].y, t1r[k].y);
            t1r[k].z = fmaf(u1v, xa[k].z, t1r[k].z);
            t1r[k].w = fmaf(u1v, xa[k].w, t1r[k].w);
            rh.x = fmaf(u3r[k], xa[k].x, rh.x);
            rh.y = fmaf(u3r[k], xa[k].y, rh.y);
            rh.z = fmaf(u3r[k], xa[k].z, rh.z);
            rh.w = fmaf(u3r[k], xa[k].w, rh.w);
        }
        *reinterpret_cast<float4*>(&rp[cg][t4 * 4]) = rh;
        __syncthreads();

        if (tid < NT) {
            float s = 0.f;
#pragma unroll
            for (int g = 0; g < 16; ++g) s += rp[g][tid];
            rhs_s[tid] = s;
        }
        __syncthreads();

        const float4 r4 = *reinterpret_cast<const float4*>(&rhs_s[t4 * 4]);
#pragma unroll
        for (int k = 0; k < 4; ++k) {
            const float u2v = U2s[c0 + k][vi];
            mr[k].x = fmaf(u2v, r4.x, mr[k].x);
            mr[k].y = fmaf(u2v, r4.y, mr[k].y);
            mr[k].z = fmaf(u2v, r4.z, mr[k].z);
            mr[k].w = fmaf(u2v, r4.w, mr[k].w);
        }
        __syncthreads();   // protect rp/rhs_s before next iteration's writes
    }

    float* t1b = tmp1g + (size_t)b * NC * NT;
    float* mb  = Mg    + (size_t)b * NC * NT;
#pragma unroll
    for (int k = 0; k < 4; ++k) {
        const int off = (c0 + k) * NT + t4 * 4;
        atomicAdd(&t1b[off + 0], t1r[k].x);
        atomicAdd(&t1b[off + 1], t1r[k].y);
        atomicAdd(&t1b[off + 2], t1r[k].z);
        atomicAdd(&t1b[off + 3], t1r[k].w);
        atomicAdd(&mb[off + 0], mr[k].x);
        atomicAdd(&mb[off + 1], mr[k].y);
        atomicAdd(&mb[off + 2], mr[k].z);
        atomicAdd(&mb[off + 3], mr[k].w);
    }
}

// ---------------------------------------------------------------------------
// Kernel 2: per-b epilogue (tiny). product = tmp1^T(c,t) · M(c,u); sigmoid(+b_e);
// E = V_e @ sig; softmax over t (axis=1) per column u.
// One block per b, 256 threads (4 waves; wave w owns t rows w*16..w*16+15).
// ---------------------------------------------------------------------------
__global__ __launch_bounds__(256) void k2_epilogue(
    const float* __restrict__ tmp1g,  // (B, C, T)
    const float* __restrict__ Mg,     // (B, C, T)
    const float* __restrict__ b_e,    // (1, T, T)
    const float* __restrict__ V_e,    // (B, T, T)
    float* __restrict__ out)          // (B, T, T)
{
    const int b = blockIdx.x;
    const int tid = threadIdx.x;

    __shared__ float t1[NC * NT];
    __shared__ float Mb[NC * NT];
    __shared__ float P[NT * NT];
    __shared__ float Eb[NT * NT];

    const float* t1g = tmp1g + (size_t)b * NC * NT;
    const float* mgb = Mg    + (size_t)b * NC * NT;
    for (int i = tid * 4; i < NC * NT; i += 1024) {
        *reinterpret_cast<float4*>(&t1[i]) = *reinterpret_cast<const float4*>(&t1g[i]);
        *reinterpret_cast<float4*>(&Mb[i]) = *reinterpret_cast<const float4*>(&mgb[i]);
    }
    __syncthreads();

    const int u  = tid & 63;
    const int tg = tid >> 6;   // wave id, 0..3

    // product + sigmoid
    for (int i = 0; i < 16; ++i) {
        const int t = tg * 16 + i;
        float acc = 0.f;
#pragma unroll 8
        for (int c = 0; c < NC; ++c)
            acc = fmaf(t1[c * NT + t], Mb[c * NT + u], acc);
        const float z = acc + b_e[t * NT + u];
        P[t * NT + u] = 1.0f / (1.0f + expf(-z));
    }
    __syncthreads();

    // E = V_e @ P
    const float* veb = V_e + (size_t)b * NT * NT;
    for (int i = 0; i < 16; ++i) {
        const int t = tg * 16 + i;
        float acc = 0.f;
#pragma unroll 8
        for (int s = 0; s < NT; ++s)
            acc = fmaf(veb[t * NT + s], P[s * NT + u], acc);
        Eb[t * NT + u] = acc;
    }
    __syncthreads();

    // softmax over t for each column u
    if (tid < NT) {
        const int uu = tid;
        float m = -INFINITY;
        for (int t = 0; t < NT; ++t) m = fmaxf(m, Eb[t * NT + uu]);
        float ssum = 0.f;
        for (int t = 0; t < NT; ++t) {
            const float e = expf(Eb[t * NT + uu] - m);
            Eb[t * NT + uu] = e;
            ssum += e;
        }
        const float inv = 1.0f / ssum;
        for (int t = 0; t < NT; ++t)
            out[(size_t)b * NT * NT + t * NT + uu] = Eb[t * NT + uu] * inv;
    }
}

extern "C" void kernel_launch(void* const* d_in, const int* in_sizes, int n_in,
                              void* d_out, int out_size, void* d_ws, size_t ws_size,
                              hipStream_t stream) {
    const float* x   = (const float*)d_in[0];
    const float* U1  = (const float*)d_in[1];
    const float* U2  = (const float*)d_in[2];
    const float* U3  = (const float*)d_in[3];
    const float* b_e = (const float*)d_in[4];
    const float* V_e = (const float*)d_in[5];
    float* out = (float*)d_out;

    float* tmp1 = (float*)d_ws;
    float* Mg   = tmp1 + (size_t)NB * NC * NT;

    // workspace is poisoned once and never re-poisoned; we accumulate with
    // atomics, so zero it every call.
    hipMemsetAsync(d_ws, 0, (size_t)2 * NB * NC * NT * sizeof(float), stream);

    k1_pass_x<<<NB * (NV / VC), 256, 0, stream>>>(x, U1, U2, U3, tmp1, Mg);
    k2_epilogue<<<NB, 256, 0, stream>>>(tmp1, Mg, b_e, V_e, out);
}